// Round 5
// baseline (527.529 us; speedup 1.0000x reference)
//
#include <hip/hip_runtime.h>
#include <math.h>

#define N_NODES 50000
#define N_EDGES 1600000
#define N_GRAPH 500
#define NXCD 8

// ---------- helpers ----------
__device__ __forceinline__ unsigned f2u_ord(float f) {
    unsigned b = __float_as_uint(f);
    return (b & 0x80000000u) ? ~b : (b | 0x80000000u);
}
__device__ __forceinline__ float u2f_ord(unsigned u) {
    return __uint_as_float((u & 0x80000000u) ? (u ^ 0x80000000u) : ~u);
}
__device__ __forceinline__ float rl(float v, int k) {
    return __int_as_float(__builtin_amdgcn_readlane(__float_as_int(v), k));
}

// ---------- hist: XCD-range-localized atomics (no rank array) ----------
__global__ __launch_bounds__(256) void hist_kernel(const int* __restrict__ dst,
                                                   int* __restrict__ deg,
                                                   int E, int nodesPerRange, int chunks) {
    int range = blockIdx.x & (NXCD - 1);
    int chunk = blockIdx.x >> 3;
    int lo = range * nodesPerRange;
    int hi = lo + nodesPerRange;
    int per = (E + chunks - 1) / chunks;
    int s = chunk * per;
    int e_end = min(s + per, E);
    for (int e = s + threadIdx.x; e < e_end; e += 256) {
        int d = dst[e];
        if (d >= lo && d < hi) atomicAdd(&deg[d], 1);
    }
}

// ---------- 3-phase scan ----------
__global__ __launch_bounds__(1024) void scan1_kernel(const int* __restrict__ deg,
                                                     int* __restrict__ part, int N) {
    int i = blockIdx.x * 1024 + threadIdx.x;
    int v = (i < N) ? deg[i] : 0;
#pragma unroll
    for (int o = 32; o >= 1; o >>= 1) v += __shfl_xor(v, o);
    __shared__ int red[16];
    if ((threadIdx.x & 63) == 0) red[threadIdx.x >> 6] = v;
    __syncthreads();
    if (threadIdx.x == 0) {
        int s = 0;
#pragma unroll
        for (int k = 0; k < 16; k++) s += red[k];
        part[blockIdx.x] = s;
    }
}

__global__ void scan2_kernel(int* __restrict__ part, int nb) {
    int lane = threadIdx.x;
    int v = (lane < nb) ? part[lane] : 0;
    int orig = v;
#pragma unroll
    for (int o = 1; o < 64; o <<= 1) {
        int t = __shfl_up(v, o);
        if (lane >= o) v += t;
    }
    if (lane < nb) part[lane] = v - orig;
    if (lane == nb - 1) part[nb] = v;
}

__global__ __launch_bounds__(1024) void scan3_kernel(const int* __restrict__ deg,
                                                     const int* __restrict__ part,
                                                     int* __restrict__ rowptr, int N) {
    int i = blockIdx.x * 1024 + threadIdx.x;
    int lane = threadIdx.x & 63;
    int w = threadIdx.x >> 6;
    int v = (i < N) ? deg[i] : 0;
    int inc = v;
#pragma unroll
    for (int o = 1; o < 64; o <<= 1) {
        int t = __shfl_up(inc, o);
        if (lane >= o) inc += t;
    }
    __shared__ int wsum[16];
    if (lane == 63) wsum[w] = inc;
    __syncthreads();
    if (threadIdx.x < 16) {
        int x = wsum[threadIdx.x];
        int xo = x;
#pragma unroll
        for (int o = 1; o < 16; o <<= 1) {
            int t = __shfl_up(x, o);
            if ((int)threadIdx.x >= o) x += t;
        }
        wsum[threadIdx.x] = x - xo;
    }
    __syncthreads();
    int base = part[blockIdx.x] + wsum[w];
    if (i < N) {
        rowptr[i] = base + inc - v;
        if (i == N - 1) rowptr[N] = base + inc;
    }
}

// ---------- fill: XCD-range-localized cursor atomics + scatter ----------
__global__ __launch_bounds__(256) void fill_kernel(const int* __restrict__ src,
                                                   const int* __restrict__ dst,
                                                   int* __restrict__ cursor,
                                                   int* __restrict__ csr_src,
                                                   int E, int nodesPerRange, int chunks) {
    int range = blockIdx.x & (NXCD - 1);
    int chunk = blockIdx.x >> 3;
    int lo = range * nodesPerRange;
    int hi = lo + nodesPerRange;
    int per = (E + chunks - 1) / chunks;
    int s = chunk * per;
    int e_end = min(s + per, E);
    for (int e = s + threadIdx.x; e < e_end; e += 256) {
        int d = dst[e];
        if (d >= lo && d < hi) {
            int pos = atomicAdd(&cursor[d], 1);
            csr_src[pos] = src[e];
        }
    }
}

// ---------- aggregation: u[d] = y[d] + sum y[src]; float4 lanes, 8 loads in flight ----------
__global__ __launch_bounds__(256) void agg_kernel(const float* __restrict__ y,
                                                  const int* __restrict__ rowptr,
                                                  const int* __restrict__ csr_src,
                                                  float* __restrict__ u, int N) {
    int wid = (blockIdx.x * 256 + threadIdx.x) >> 6;
    int lane = threadIdx.x & 63;
    if (wid >= N) return;
    int q = lane >> 4;   // edge slot 0..3
    int r = lane & 15;   // feature quad 0..15
    int start = rowptr[wid];
    int end = rowptr[wid + 1];
    float4 acc = make_float4(0.f, 0.f, 0.f, 0.f);
    int j = start;
    for (; j + 32 <= end; j += 32) {
        int s0 = csr_src[j + q];
        int s1 = csr_src[j + 4 + q];
        int s2 = csr_src[j + 8 + q];
        int s3 = csr_src[j + 12 + q];
        int s4 = csr_src[j + 16 + q];
        int s5 = csr_src[j + 20 + q];
        int s6 = csr_src[j + 24 + q];
        int s7 = csr_src[j + 28 + q];
        float4 v0 = *(const float4*)(y + s0 * 64 + r * 4);
        float4 v1 = *(const float4*)(y + s1 * 64 + r * 4);
        float4 v2 = *(const float4*)(y + s2 * 64 + r * 4);
        float4 v3 = *(const float4*)(y + s3 * 64 + r * 4);
        float4 v4 = *(const float4*)(y + s4 * 64 + r * 4);
        float4 v5 = *(const float4*)(y + s5 * 64 + r * 4);
        float4 v6 = *(const float4*)(y + s6 * 64 + r * 4);
        float4 v7 = *(const float4*)(y + s7 * 64 + r * 4);
        acc.x += ((v0.x + v1.x) + (v2.x + v3.x)) + ((v4.x + v5.x) + (v6.x + v7.x));
        acc.y += ((v0.y + v1.y) + (v2.y + v3.y)) + ((v4.y + v5.y) + (v6.y + v7.y));
        acc.z += ((v0.z + v1.z) + (v2.z + v3.z)) + ((v4.z + v5.z) + (v6.z + v7.z));
        acc.w += ((v0.w + v1.w) + (v2.w + v3.w)) + ((v4.w + v5.w) + (v6.w + v7.w));
    }
    // tail: < 32 edges, predicated groups of 4
#pragma unroll
    for (int m = 0; m < 8; m++) {
        int e = j + 4 * m + q;
        if (e < end) {
            int s = csr_src[e];
            float4 v = *(const float4*)(y + s * 64 + r * 4);
            acc.x += v.x; acc.y += v.y; acc.z += v.z; acc.w += v.w;
        }
    }
    acc.x += __shfl_xor(acc.x, 16);
    acc.y += __shfl_xor(acc.y, 16);
    acc.z += __shfl_xor(acc.z, 16);
    acc.w += __shfl_xor(acc.w, 16);
    acc.x += __shfl_xor(acc.x, 32);
    acc.y += __shfl_xor(acc.y, 32);
    acc.z += __shfl_xor(acc.z, 32);
    acc.w += __shfl_xor(acc.w, 32);
    if (lane < 16) {
        float4 self = *(const float4*)(y + wid * 64 + r * 4);
        acc.x += self.x; acc.y += self.y; acc.z += self.z; acc.w += self.w;
        *(float4*)(u + wid * 64 + r * 4) = acc;
    }
}

// ---------- gemm0: y0 = x @ W1_0 (N x 128 -> N x 64), register weights ----------
__global__ __launch_bounds__(256) void gemm0_kernel(const float* __restrict__ x,
                                                    const float* __restrict__ W1,
                                                    float* __restrict__ y0,
                                                    int N, int totalWaves) {
    int lane = threadIdx.x & 63;
    int wid = (blockIdx.x * 256 + threadIdx.x) >> 6;
    float w[64];
#pragma unroll
    for (int k = 0; k < 64; k++) w[k] = W1[k * 64 + lane];
    for (int node = wid; node < N; node += totalWaves) {
        float xa = x[node * 128 + lane];
        float a0 = 0.f, a1 = 0.f, a2 = 0.f, a3 = 0.f;
#pragma unroll
        for (int k = 0; k < 64; k += 4) {
            a0 = fmaf(rl(xa, k + 0), w[k + 0], a0);
            a1 = fmaf(rl(xa, k + 1), w[k + 1], a1);
            a2 = fmaf(rl(xa, k + 2), w[k + 2], a2);
            a3 = fmaf(rl(xa, k + 3), w[k + 3], a3);
        }
        y0[node * 64 + lane] = (a0 + a1) + (a2 + a3);
    }
#pragma unroll
    for (int k = 0; k < 64; k++) w[k] = W1[(64 + k) * 64 + lane];
    for (int node = wid; node < N; node += totalWaves) {
        float xb = x[node * 128 + 64 + lane];
        float a0 = 0.f, a1 = 0.f, a2 = 0.f, a3 = 0.f;
#pragma unroll
        for (int k = 0; k < 64; k += 4) {
            a0 = fmaf(rl(xb, k + 0), w[k + 0], a0);
            a1 = fmaf(rl(xb, k + 1), w[k + 1], a1);
            a2 = fmaf(rl(xb, k + 2), w[k + 2], a2);
            a3 = fmaf(rl(xb, k + 3), w[k + 3], a3);
        }
        y0[node * 64 + lane] += (a0 + a1) + (a2 + a3);
    }
}

// ---------- fused mlpAB (layers 0,1): t=relu(u+b1); h=relu(t@W2+b2);
//            score += h.Wm; ynext = h @ W1next ----------
template <int LAYER>
__global__ __launch_bounds__(256) void mlpAB_kernel(const float* __restrict__ u,
                                                    const float* __restrict__ b1,
                                                    const float* __restrict__ W2,
                                                    const float* __restrict__ b2,
                                                    const float* __restrict__ W1n,
                                                    const float* __restrict__ Wm,
                                                    float* __restrict__ ynext,
                                                    float* __restrict__ score,
                                                    int N, int totalWaves) {
    int lane = threadIdx.x & 63;
    int wid = (blockIdx.x * 256 + threadIdx.x) >> 6;
    float w2[64], w1[64];
#pragma unroll
    for (int k = 0; k < 64; k++) w2[k] = W2[k * 64 + lane];
#pragma unroll
    for (int k = 0; k < 64; k++) w1[k] = W1n[k * 64 + lane];
    float bb1 = b1[lane], bb2 = b2[lane], wm = Wm[LAYER * 64 + lane];

    int node = wid;
    float uin = (node < N) ? u[node * 64 + lane] : 0.f;
    for (; node < N; node += totalWaves) {
        int nn = node + totalWaves;
        float unext = (nn < N) ? u[nn * 64 + lane] : 0.f;
        float t = fmaxf(uin + bb1, 0.f);
        float a0 = 0.f, a1 = 0.f, a2 = 0.f, a3 = 0.f;
#pragma unroll
        for (int k = 0; k < 64; k += 4) {
            a0 = fmaf(rl(t, k + 0), w2[k + 0], a0);
            a1 = fmaf(rl(t, k + 1), w2[k + 1], a1);
            a2 = fmaf(rl(t, k + 2), w2[k + 2], a2);
            a3 = fmaf(rl(t, k + 3), w2[k + 3], a3);
        }
        float h = fmaxf(bb2 + ((a0 + a1) + (a2 + a3)), 0.f);
        float p = h * wm;
#pragma unroll
        for (int o = 32; o >= 1; o >>= 1) p += __shfl_xor(p, o);
        if (lane == 0) {
            if (LAYER == 0) score[node] = p;
            else score[node] += p;
        }
        float y0 = 0.f, y1 = 0.f, y2 = 0.f, y3 = 0.f;
#pragma unroll
        for (int k = 0; k < 64; k += 4) {
            y0 = fmaf(rl(h, k + 0), w1[k + 0], y0);
            y1 = fmaf(rl(h, k + 1), w1[k + 1], y1);
            y2 = fmaf(rl(h, k + 2), w1[k + 2], y2);
            y3 = fmaf(rl(h, k + 3), w1[k + 3], y3);
        }
        ynext[node * 64 + lane] = (y0 + y1) + (y2 + y3);
        uin = unext;
    }
}

// ---------- mlpA2 (layer 2): no ynext, no relu on h ----------
__global__ __launch_bounds__(256) void mlpA2_kernel(const float* __restrict__ u,
                                                    const float* __restrict__ b1,
                                                    const float* __restrict__ W2,
                                                    const float* __restrict__ b2,
                                                    const float* __restrict__ Wm,
                                                    float* __restrict__ score,
                                                    int N, int totalWaves) {
    int lane = threadIdx.x & 63;
    int wid = (blockIdx.x * 256 + threadIdx.x) >> 6;
    float w2[64];
#pragma unroll
    for (int k = 0; k < 64; k++) w2[k] = W2[k * 64 + lane];
    float bb1 = b1[lane], bb2 = b2[lane], wm = Wm[2 * 64 + lane];

    int node = wid;
    float uin = (node < N) ? u[node * 64 + lane] : 0.f;
    for (; node < N; node += totalWaves) {
        int nn = node + totalWaves;
        float unext = (nn < N) ? u[nn * 64 + lane] : 0.f;
        float t = fmaxf(uin + bb1, 0.f);
        float a0 = 0.f, a1 = 0.f, a2 = 0.f, a3 = 0.f;
#pragma unroll
        for (int k = 0; k < 64; k += 4) {
            a0 = fmaf(rl(t, k + 0), w2[k + 0], a0);
            a1 = fmaf(rl(t, k + 1), w2[k + 1], a1);
            a2 = fmaf(rl(t, k + 2), w2[k + 2], a2);
            a3 = fmaf(rl(t, k + 3), w2[k + 3], a3);
        }
        float h = bb2 + ((a0 + a1) + (a2 + a3));
        float p = h * wm;
#pragma unroll
        for (int o = 32; o >= 1; o >>= 1) p += __shfl_xor(p, o);
        if (lane == 0) score[node] += p;
        uin = unext;
    }
}

// ---------- edge softmax + new_score ----------
__global__ __launch_bounds__(256) void edge_softmax_kernel(const float* __restrict__ score,
                                                           const int* __restrict__ rowptr,
                                                           const int* __restrict__ csr_src,
                                                           const float* __restrict__ bm,
                                                           float* __restrict__ nsf, int N) {
    int wid = (blockIdx.x * blockDim.x + threadIdx.x) >> 6;
    int lane = threadIdx.x & 63;
    if (wid >= N) return;
    float b = bm[0];
    float sd = score[wid] + b;
    int start = rowptr[wid];
    int end = rowptr[wid + 1];
    bool has0 = (start + lane < end);
    float ss0 = 0.f;
    float m = -INFINITY;
    if (has0) {
        ss0 = score[csr_src[start + lane]] + b;
        m = ss0 * sd;
    }
    for (int j = start + 64 + lane; j < end; j += 64) {
        float ss = score[csr_src[j]] + b;
        m = fmaxf(m, ss * sd);
    }
#pragma unroll
    for (int o = 32; o >= 1; o >>= 1) m = fmaxf(m, __shfl_xor(m, o));
    float se = 0.f, swe = 0.f;
    if (m > -INFINITY) {
        if (has0) {
            float e0 = expf(ss0 * sd - m);
            se += e0;
            swe += ss0 * e0;
        }
        for (int j = start + 64 + lane; j < end; j += 64) {
            float ss = score[csr_src[j]] + b;
            float e = expf(ss * sd - m);
            se += e;
            swe += ss * e;
        }
#pragma unroll
        for (int o = 32; o >= 1; o >>= 1) {
            se += __shfl_xor(se, o);
            swe += __shfl_xor(swe, o);
        }
    }
    float ns = (se > 0.f) ? (swe / se) : 0.f;
    if (lane == 0) nsf[wid] = sd + ns;
}

// ---------- graph-segment softmax ----------
__global__ void gmax_kernel(const float* __restrict__ nsf, const int* __restrict__ batch,
                            unsigned* __restrict__ gmaxu, int N) {
    int i = blockIdx.x * blockDim.x + threadIdx.x;
    if (i < N) atomicMax(&gmaxu[batch[i]], f2u_ord(nsf[i]));
}
__global__ void gexp_kernel(const float* __restrict__ nsf, const int* __restrict__ batch,
                            const unsigned* __restrict__ gmaxu, float* __restrict__ gsum,
                            float* __restrict__ out, int N) {
    int i = blockIdx.x * blockDim.x + threadIdx.x;
    if (i < N) {
        int b = batch[i];
        float m = u2f_ord(gmaxu[b]);
        float e = expf(nsf[i] - m);
        out[i] = e;
        atomicAdd(&gsum[b], e);
    }
}
__global__ void gdiv_kernel(const int* __restrict__ batch, const float* __restrict__ gsum,
                            float* __restrict__ out, int N) {
    int i = blockIdx.x * blockDim.x + threadIdx.x;
    if (i < N) out[i] /= gsum[batch[i]];
}

extern "C" void kernel_launch(void* const* d_in, const int* in_sizes, int n_in,
                              void* d_out, int out_size, void* d_ws, size_t ws_size,
                              hipStream_t stream) {
    const int N = N_NODES, E = N_EDGES, G = N_GRAPH;

    const float* x = (const float*)d_in[0];
    const int* ei = (const int*)d_in[1];
    const int* batch = (const int*)d_in[2];
    const float* W1a[3] = {(const float*)d_in[3], (const float*)d_in[7], (const float*)d_in[11]};
    const float* b1a[3] = {(const float*)d_in[4], (const float*)d_in[8], (const float*)d_in[12]};
    const float* W2a[3] = {(const float*)d_in[5], (const float*)d_in[9], (const float*)d_in[13]};
    const float* b2a[3] = {(const float*)d_in[6], (const float*)d_in[10], (const float*)d_in[14]};
    const float* Wm = (const float*)d_in[15];
    const float* bm = (const float*)d_in[16];
    float* out = (float*)d_out;

    const int* srcp = ei;
    const int* dstp = ei + E;

    // workspace layout
    float* yA = (float*)d_ws;                   // N*64
    float* yB = yA + (size_t)N * 64;            // N*64
    float* ubuf = yB + (size_t)N * 64;          // N*64
    float* score = ubuf + (size_t)N * 64;       // N
    float* nsf = score + N;                     // N
    float* gsum = nsf + N;                      // G
    unsigned* gmaxu = (unsigned*)(gsum + G);    // G
    int* deg = (int*)(gmaxu + G);               // N
    int* rowptr = deg + N;                      // N+1
    int* part = rowptr + N + 1;                 // 64
    int* cursor = part + 64;                    // N
    int* csr_src = cursor + N;                  // E

    hipMemsetAsync(deg, 0, sizeof(int) * N, stream);
    hipMemsetAsync(gmaxu, 0, sizeof(unsigned) * G, stream);
    hipMemsetAsync(gsum, 0, sizeof(float) * G, stream);

    const int chunks = 128;
    const int nodesPerRange = N / NXCD;  // 6250
    hist_kernel<<<chunks * NXCD, 256, 0, stream>>>(dstp, deg, E, nodesPerRange, chunks);

    const int nbScan = (N + 1023) / 1024;  // 49
    scan1_kernel<<<nbScan, 1024, 0, stream>>>(deg, part, N);
    scan2_kernel<<<1, 64, 0, stream>>>(part, nbScan);
    scan3_kernel<<<nbScan, 1024, 0, stream>>>(deg, part, rowptr, N);

    hipMemcpyAsync(cursor, rowptr, sizeof(int) * N, hipMemcpyDeviceToDevice, stream);
    fill_kernel<<<chunks * NXCD, 256, 0, stream>>>(srcp, dstp, cursor, csr_src,
                                                   E, nodesPerRange, chunks);

    const int gw = 4096;
    gemm0_kernel<<<1024, 256, 0, stream>>>(x, W1a[0], yA, N, gw);

    int aggBlocks = (N + 3) / 4;

    agg_kernel<<<aggBlocks, 256, 0, stream>>>(yA, rowptr, csr_src, ubuf, N);
    mlpAB_kernel<0><<<1024, 256, 0, stream>>>(ubuf, b1a[0], W2a[0], b2a[0], W1a[1], Wm, yB, score, N, gw);

    agg_kernel<<<aggBlocks, 256, 0, stream>>>(yB, rowptr, csr_src, ubuf, N);
    mlpAB_kernel<1><<<1024, 256, 0, stream>>>(ubuf, b1a[1], W2a[1], b2a[1], W1a[2], Wm, yA, score, N, gw);

    agg_kernel<<<aggBlocks, 256, 0, stream>>>(yA, rowptr, csr_src, ubuf, N);
    mlpA2_kernel<<<1024, 256, 0, stream>>>(ubuf, b1a[2], W2a[2], b2a[2], Wm, score, N, gw);

    edge_softmax_kernel<<<(N + 3) / 4, 256, 0, stream>>>(score, rowptr, csr_src, bm, nsf, N);

    int nb = (N + 255) / 256;
    gmax_kernel<<<nb, 256, 0, stream>>>(nsf, batch, gmaxu, N);
    gexp_kernel<<<nb, 256, 0, stream>>>(nsf, batch, gmaxu, gsum, out, N);
    gdiv_kernel<<<nb, 256, 0, stream>>>(batch, gsum, out, N);
}

// Round 6
// 431.321 us; speedup vs baseline: 1.2231x; 1.2231x over previous
//
#include <hip/hip_runtime.h>
#include <math.h>

#define N_NODES 50000
#define N_EDGES 1600000
#define N_GRAPH 500
#define CHUNKS 64
#define FILL_SUB 16

// ---------- helpers ----------
__device__ __forceinline__ unsigned f2u_ord(float f) {
    unsigned b = __float_as_uint(f);
    return (b & 0x80000000u) ? ~b : (b | 0x80000000u);
}
__device__ __forceinline__ float u2f_ord(unsigned u) {
    return __uint_as_float((u & 0x80000000u) ? (u ^ 0x80000000u) : ~u);
}
__device__ __forceinline__ float rl(float v, int k) {
    return __int_as_float(__builtin_amdgcn_readlane(__float_as_int(v), k));
}

// ---------- hist: per-chunk LDS histogram (packed 2x16-bit) + local rank, no global atomics
__global__ __launch_bounds__(1024) void hist_kernel(const int* __restrict__ dst,
                                                    unsigned short* __restrict__ hist,
                                                    unsigned short* __restrict__ lr, int E) {
    __shared__ unsigned packed[N_NODES / 2];  // 100 KB
    for (int i = threadIdx.x; i < N_NODES / 2; i += 1024) packed[i] = 0;
    __syncthreads();
    int c = blockIdx.x;
    int per = E / CHUNKS;  // 25000
    int s = c * per;
    for (int e = s + threadIdx.x; e < s + per; e += 1024) {
        int d = dst[e];
        int sh = (d & 1) * 16;
        unsigned old = atomicAdd(&packed[d >> 1], 1u << sh);
        lr[e] = (unsigned short)((old >> sh) & 0xffffu);
    }
    __syncthreads();
    unsigned short* hc = hist + (size_t)c * N_NODES;
    for (int i = threadIdx.x; i < N_NODES; i += 1024) {
        unsigned w = packed[i >> 1];
        hc[i] = (unsigned short)((w >> ((i & 1) * 16)) & 0xffffu);
    }
}

// ---------- base: per-node exclusive scan over chunk partials; emits deg ----------
__global__ __launch_bounds__(256) void base_kernel(const unsigned short* __restrict__ hist,
                                                   unsigned short* __restrict__ base,
                                                   int* __restrict__ deg, int N) {
    int d = blockIdx.x * 256 + threadIdx.x;
    if (d >= N) return;
    int run = 0;
#pragma unroll 8
    for (int c = 0; c < CHUNKS; c++) {
        int v = hist[(size_t)c * N + d];
        base[(size_t)c * N + d] = (unsigned short)run;
        run += v;
    }
    deg[d] = run;
}

// ---------- 3-phase scan ----------
__global__ __launch_bounds__(1024) void scan1_kernel(const int* __restrict__ deg,
                                                     int* __restrict__ part, int N) {
    int i = blockIdx.x * 1024 + threadIdx.x;
    int v = (i < N) ? deg[i] : 0;
#pragma unroll
    for (int o = 32; o >= 1; o >>= 1) v += __shfl_xor(v, o);
    __shared__ int red[16];
    if ((threadIdx.x & 63) == 0) red[threadIdx.x >> 6] = v;
    __syncthreads();
    if (threadIdx.x == 0) {
        int s = 0;
#pragma unroll
        for (int k = 0; k < 16; k++) s += red[k];
        part[blockIdx.x] = s;
    }
}

__global__ void scan2_kernel(int* __restrict__ part, int nb) {
    int lane = threadIdx.x;
    int v = (lane < nb) ? part[lane] : 0;
    int orig = v;
#pragma unroll
    for (int o = 1; o < 64; o <<= 1) {
        int t = __shfl_up(v, o);
        if (lane >= o) v += t;
    }
    if (lane < nb) part[lane] = v - orig;
    if (lane == nb - 1) part[nb] = v;
}

__global__ __launch_bounds__(1024) void scan3_kernel(const int* __restrict__ deg,
                                                     const int* __restrict__ part,
                                                     int* __restrict__ rowptr, int N) {
    int i = blockIdx.x * 1024 + threadIdx.x;
    int lane = threadIdx.x & 63;
    int w = threadIdx.x >> 6;
    int v = (i < N) ? deg[i] : 0;
    int inc = v;
#pragma unroll
    for (int o = 1; o < 64; o <<= 1) {
        int t = __shfl_up(inc, o);
        if (lane >= o) inc += t;
    }
    __shared__ int wsum[16];
    if (lane == 63) wsum[w] = inc;
    __syncthreads();
    if (threadIdx.x < 16) {
        int x = wsum[threadIdx.x];
        int xo = x;
#pragma unroll
        for (int o = 1; o < 16; o <<= 1) {
            int t = __shfl_up(x, o);
            if ((int)threadIdx.x >= o) x += t;
        }
        wsum[threadIdx.x] = x - xo;
    }
    __syncthreads();
    int base = part[blockIdx.x] + wsum[w];
    if (i < N) {
        rowptr[i] = base + inc - v;
        if (i == N - 1) rowptr[N] = base + inc;
    }
}

// ---------- fill: atomic-free scatter via rowptr + base + lr ----------
__global__ __launch_bounds__(256) void fill_kernel(const int* __restrict__ src,
                                                   const int* __restrict__ dst,
                                                   const unsigned short* __restrict__ lr,
                                                   const unsigned short* __restrict__ base,
                                                   const int* __restrict__ rowptr,
                                                   int* __restrict__ csr_src, int E) {
    int c = blockIdx.x / FILL_SUB;
    int s = blockIdx.x % FILL_SUB;
    int per = E / CHUNKS;
    int e0 = c * per + (s * per) / FILL_SUB;
    int e1 = c * per + ((s + 1) * per) / FILL_SUB;
    const unsigned short* basec = base + (size_t)c * N_NODES;
    for (int e = e0 + threadIdx.x; e < e1; e += 256) {
        int d = dst[e];
        int pos = rowptr[d] + (int)basec[d] + (int)lr[e];
        csr_src[pos] = src[e];
    }
}

// ---------- aggregation: u[d] = y[d] + sum y[src]; float4 lanes, 8 loads in flight ----------
__global__ __launch_bounds__(256) void agg_kernel(const float* __restrict__ y,
                                                  const int* __restrict__ rowptr,
                                                  const int* __restrict__ csr_src,
                                                  float* __restrict__ u, int N) {
    int wid = (blockIdx.x * 256 + threadIdx.x) >> 6;
    int lane = threadIdx.x & 63;
    if (wid >= N) return;
    int q = lane >> 4;   // edge slot 0..3
    int r = lane & 15;   // feature quad 0..15
    int start = rowptr[wid];
    int end = rowptr[wid + 1];
    float4 acc = make_float4(0.f, 0.f, 0.f, 0.f);
    int j = start;
    for (; j + 32 <= end; j += 32) {
        int s0 = csr_src[j + q];
        int s1 = csr_src[j + 4 + q];
        int s2 = csr_src[j + 8 + q];
        int s3 = csr_src[j + 12 + q];
        int s4 = csr_src[j + 16 + q];
        int s5 = csr_src[j + 20 + q];
        int s6 = csr_src[j + 24 + q];
        int s7 = csr_src[j + 28 + q];
        float4 v0 = *(const float4*)(y + s0 * 64 + r * 4);
        float4 v1 = *(const float4*)(y + s1 * 64 + r * 4);
        float4 v2 = *(const float4*)(y + s2 * 64 + r * 4);
        float4 v3 = *(const float4*)(y + s3 * 64 + r * 4);
        float4 v4 = *(const float4*)(y + s4 * 64 + r * 4);
        float4 v5 = *(const float4*)(y + s5 * 64 + r * 4);
        float4 v6 = *(const float4*)(y + s6 * 64 + r * 4);
        float4 v7 = *(const float4*)(y + s7 * 64 + r * 4);
        acc.x += ((v0.x + v1.x) + (v2.x + v3.x)) + ((v4.x + v5.x) + (v6.x + v7.x));
        acc.y += ((v0.y + v1.y) + (v2.y + v3.y)) + ((v4.y + v5.y) + (v6.y + v7.y));
        acc.z += ((v0.z + v1.z) + (v2.z + v3.z)) + ((v4.z + v5.z) + (v6.z + v7.z));
        acc.w += ((v0.w + v1.w) + (v2.w + v3.w)) + ((v4.w + v5.w) + (v6.w + v7.w));
    }
#pragma unroll
    for (int m = 0; m < 8; m++) {
        int e = j + 4 * m + q;
        if (e < end) {
            int s = csr_src[e];
            float4 v = *(const float4*)(y + s * 64 + r * 4);
            acc.x += v.x; acc.y += v.y; acc.z += v.z; acc.w += v.w;
        }
    }
    acc.x += __shfl_xor(acc.x, 16);
    acc.y += __shfl_xor(acc.y, 16);
    acc.z += __shfl_xor(acc.z, 16);
    acc.w += __shfl_xor(acc.w, 16);
    acc.x += __shfl_xor(acc.x, 32);
    acc.y += __shfl_xor(acc.y, 32);
    acc.z += __shfl_xor(acc.z, 32);
    acc.w += __shfl_xor(acc.w, 32);
    if (lane < 16) {
        float4 self = *(const float4*)(y + wid * 64 + r * 4);
        acc.x += self.x; acc.y += self.y; acc.z += self.z; acc.w += self.w;
        *(float4*)(u + wid * 64 + r * 4) = acc;
    }
}

// ---------- gemm0: y0 = x @ W1_0 (N x 128 -> N x 64), register weights ----------
__global__ __launch_bounds__(256) void gemm0_kernel(const float* __restrict__ x,
                                                    const float* __restrict__ W1,
                                                    float* __restrict__ y0,
                                                    int N, int totalWaves) {
    int lane = threadIdx.x & 63;
    int wid = (blockIdx.x * 256 + threadIdx.x) >> 6;
    float w[64];
#pragma unroll
    for (int k = 0; k < 64; k++) w[k] = W1[k * 64 + lane];
    for (int node = wid; node < N; node += totalWaves) {
        float xa = x[node * 128 + lane];
        float a0 = 0.f, a1 = 0.f, a2 = 0.f, a3 = 0.f;
#pragma unroll
        for (int k = 0; k < 64; k += 4) {
            a0 = fmaf(rl(xa, k + 0), w[k + 0], a0);
            a1 = fmaf(rl(xa, k + 1), w[k + 1], a1);
            a2 = fmaf(rl(xa, k + 2), w[k + 2], a2);
            a3 = fmaf(rl(xa, k + 3), w[k + 3], a3);
        }
        y0[node * 64 + lane] = (a0 + a1) + (a2 + a3);
    }
#pragma unroll
    for (int k = 0; k < 64; k++) w[k] = W1[(64 + k) * 64 + lane];
    for (int node = wid; node < N; node += totalWaves) {
        float xb = x[node * 128 + 64 + lane];
        float a0 = 0.f, a1 = 0.f, a2 = 0.f, a3 = 0.f;
#pragma unroll
        for (int k = 0; k < 64; k += 4) {
            a0 = fmaf(rl(xb, k + 0), w[k + 0], a0);
            a1 = fmaf(rl(xb, k + 1), w[k + 1], a1);
            a2 = fmaf(rl(xb, k + 2), w[k + 2], a2);
            a3 = fmaf(rl(xb, k + 3), w[k + 3], a3);
        }
        y0[node * 64 + lane] += (a0 + a1) + (a2 + a3);
    }
}

// ---------- fused mlpAB (layers 0,1) ----------
template <int LAYER>
__global__ __launch_bounds__(256) void mlpAB_kernel(const float* __restrict__ u,
                                                    const float* __restrict__ b1,
                                                    const float* __restrict__ W2,
                                                    const float* __restrict__ b2,
                                                    const float* __restrict__ W1n,
                                                    const float* __restrict__ Wm,
                                                    float* __restrict__ ynext,
                                                    float* __restrict__ score,
                                                    int N, int totalWaves) {
    int lane = threadIdx.x & 63;
    int wid = (blockIdx.x * 256 + threadIdx.x) >> 6;
    float w2[64], w1[64];
#pragma unroll
    for (int k = 0; k < 64; k++) w2[k] = W2[k * 64 + lane];
#pragma unroll
    for (int k = 0; k < 64; k++) w1[k] = W1n[k * 64 + lane];
    float bb1 = b1[lane], bb2 = b2[lane], wm = Wm[LAYER * 64 + lane];

    int node = wid;
    float uin = (node < N) ? u[node * 64 + lane] : 0.f;
    for (; node < N; node += totalWaves) {
        int nn = node + totalWaves;
        float unext = (nn < N) ? u[nn * 64 + lane] : 0.f;
        float t = fmaxf(uin + bb1, 0.f);
        float a0 = 0.f, a1 = 0.f, a2 = 0.f, a3 = 0.f;
#pragma unroll
        for (int k = 0; k < 64; k += 4) {
            a0 = fmaf(rl(t, k + 0), w2[k + 0], a0);
            a1 = fmaf(rl(t, k + 1), w2[k + 1], a1);
            a2 = fmaf(rl(t, k + 2), w2[k + 2], a2);
            a3 = fmaf(rl(t, k + 3), w2[k + 3], a3);
        }
        float h = fmaxf(bb2 + ((a0 + a1) + (a2 + a3)), 0.f);
        float p = h * wm;
#pragma unroll
        for (int o = 32; o >= 1; o >>= 1) p += __shfl_xor(p, o);
        if (lane == 0) {
            if (LAYER == 0) score[node] = p;
            else score[node] += p;
        }
        float y0 = 0.f, y1 = 0.f, y2 = 0.f, y3 = 0.f;
#pragma unroll
        for (int k = 0; k < 64; k += 4) {
            y0 = fmaf(rl(h, k + 0), w1[k + 0], y0);
            y1 = fmaf(rl(h, k + 1), w1[k + 1], y1);
            y2 = fmaf(rl(h, k + 2), w1[k + 2], y2);
            y3 = fmaf(rl(h, k + 3), w1[k + 3], y3);
        }
        ynext[node * 64 + lane] = (y0 + y1) + (y2 + y3);
        uin = unext;
    }
}

// ---------- mlpA2 (layer 2) ----------
__global__ __launch_bounds__(256) void mlpA2_kernel(const float* __restrict__ u,
                                                    const float* __restrict__ b1,
                                                    const float* __restrict__ W2,
                                                    const float* __restrict__ b2,
                                                    const float* __restrict__ Wm,
                                                    float* __restrict__ score,
                                                    int N, int totalWaves) {
    int lane = threadIdx.x & 63;
    int wid = (blockIdx.x * 256 + threadIdx.x) >> 6;
    float w2[64];
#pragma unroll
    for (int k = 0; k < 64; k++) w2[k] = W2[k * 64 + lane];
    float bb1 = b1[lane], bb2 = b2[lane], wm = Wm[2 * 64 + lane];

    int node = wid;
    float uin = (node < N) ? u[node * 64 + lane] : 0.f;
    for (; node < N; node += totalWaves) {
        int nn = node + totalWaves;
        float unext = (nn < N) ? u[nn * 64 + lane] : 0.f;
        float t = fmaxf(uin + bb1, 0.f);
        float a0 = 0.f, a1 = 0.f, a2 = 0.f, a3 = 0.f;
#pragma unroll
        for (int k = 0; k < 64; k += 4) {
            a0 = fmaf(rl(t, k + 0), w2[k + 0], a0);
            a1 = fmaf(rl(t, k + 1), w2[k + 1], a1);
            a2 = fmaf(rl(t, k + 2), w2[k + 2], a2);
            a3 = fmaf(rl(t, k + 3), w2[k + 3], a3);
        }
        float h = bb2 + ((a0 + a1) + (a2 + a3));
        float p = h * wm;
#pragma unroll
        for (int o = 32; o >= 1; o >>= 1) p += __shfl_xor(p, o);
        if (lane == 0) score[node] += p;
        uin = unext;
    }
}

// ---------- edge softmax + new_score ----------
__global__ __launch_bounds__(256) void edge_softmax_kernel(const float* __restrict__ score,
                                                           const int* __restrict__ rowptr,
                                                           const int* __restrict__ csr_src,
                                                           const float* __restrict__ bm,
                                                           float* __restrict__ nsf, int N) {
    int wid = (blockIdx.x * blockDim.x + threadIdx.x) >> 6;
    int lane = threadIdx.x & 63;
    if (wid >= N) return;
    float b = bm[0];
    float sd = score[wid] + b;
    int start = rowptr[wid];
    int end = rowptr[wid + 1];
    bool has0 = (start + lane < end);
    float ss0 = 0.f;
    float m = -INFINITY;
    if (has0) {
        ss0 = score[csr_src[start + lane]] + b;
        m = ss0 * sd;
    }
    for (int j = start + 64 + lane; j < end; j += 64) {
        float ss = score[csr_src[j]] + b;
        m = fmaxf(m, ss * sd);
    }
#pragma unroll
    for (int o = 32; o >= 1; o >>= 1) m = fmaxf(m, __shfl_xor(m, o));
    float se = 0.f, swe = 0.f;
    if (m > -INFINITY) {
        if (has0) {
            float e0 = expf(ss0 * sd - m);
            se += e0;
            swe += ss0 * e0;
        }
        for (int j = start + 64 + lane; j < end; j += 64) {
            float ss = score[csr_src[j]] + b;
            float e = expf(ss * sd - m);
            se += e;
            swe += ss * e;
        }
#pragma unroll
        for (int o = 32; o >= 1; o >>= 1) {
            se += __shfl_xor(se, o);
            swe += __shfl_xor(swe, o);
        }
    }
    float ns = (se > 0.f) ? (swe / se) : 0.f;
    if (lane == 0) nsf[wid] = sd + ns;
}

// ---------- graph-segment softmax ----------
__global__ void gmax_kernel(const float* __restrict__ nsf, const int* __restrict__ batch,
                            unsigned* __restrict__ gmaxu, int N) {
    int i = blockIdx.x * blockDim.x + threadIdx.x;
    if (i < N) atomicMax(&gmaxu[batch[i]], f2u_ord(nsf[i]));
}
__global__ void gexp_kernel(const float* __restrict__ nsf, const int* __restrict__ batch,
                            const unsigned* __restrict__ gmaxu, float* __restrict__ gsum,
                            float* __restrict__ out, int N) {
    int i = blockIdx.x * blockDim.x + threadIdx.x;
    if (i < N) {
        int b = batch[i];
        float m = u2f_ord(gmaxu[b]);
        float e = expf(nsf[i] - m);
        out[i] = e;
        atomicAdd(&gsum[b], e);
    }
}
__global__ void gdiv_kernel(const int* __restrict__ batch, const float* __restrict__ gsum,
                            float* __restrict__ out, int N) {
    int i = blockIdx.x * blockDim.x + threadIdx.x;
    if (i < N) out[i] /= gsum[batch[i]];
}

extern "C" void kernel_launch(void* const* d_in, const int* in_sizes, int n_in,
                              void* d_out, int out_size, void* d_ws, size_t ws_size,
                              hipStream_t stream) {
    const int N = N_NODES, E = N_EDGES, G = N_GRAPH;

    const float* x = (const float*)d_in[0];
    const int* ei = (const int*)d_in[1];
    const int* batch = (const int*)d_in[2];
    const float* W1a[3] = {(const float*)d_in[3], (const float*)d_in[7], (const float*)d_in[11]};
    const float* b1a[3] = {(const float*)d_in[4], (const float*)d_in[8], (const float*)d_in[12]};
    const float* W2a[3] = {(const float*)d_in[5], (const float*)d_in[9], (const float*)d_in[13]};
    const float* b2a[3] = {(const float*)d_in[6], (const float*)d_in[10], (const float*)d_in[14]};
    const float* Wm = (const float*)d_in[15];
    const float* bm = (const float*)d_in[16];
    float* out = (float*)d_out;

    const int* srcp = ei;
    const int* dstp = ei + E;

    // workspace layout
    float* yA = (float*)d_ws;                   // N*64
    float* yB = yA + (size_t)N * 64;            // N*64
    float* ubuf = yB + (size_t)N * 64;          // N*64
    float* score = ubuf + (size_t)N * 64;       // N
    float* nsf = score + N;                     // N
    float* gsum = nsf + N;                      // G
    unsigned* gmaxu = (unsigned*)(gsum + G);    // G
    int* deg = (int*)(gmaxu + G);               // N
    int* rowptr = deg + N;                      // N+1
    int* part = rowptr + N + 1;                 // 64
    int* csr_src = part + 64;                   // E
    unsigned short* lr = (unsigned short*)(csr_src + E);          // E
    unsigned short* hist = lr + E;                                // CHUNKS*N
    unsigned short* base = hist + (size_t)CHUNKS * N;             // CHUNKS*N

    hipMemsetAsync(gmaxu, 0, sizeof(unsigned) * G, stream);
    hipMemsetAsync(gsum, 0, sizeof(float) * G, stream);

    hist_kernel<<<CHUNKS, 1024, 0, stream>>>(dstp, hist, lr, E);
    base_kernel<<<(N + 255) / 256, 256, 0, stream>>>(hist, base, deg, N);

    const int nbScan = (N + 1023) / 1024;  // 49
    scan1_kernel<<<nbScan, 1024, 0, stream>>>(deg, part, N);
    scan2_kernel<<<1, 64, 0, stream>>>(part, nbScan);
    scan3_kernel<<<nbScan, 1024, 0, stream>>>(deg, part, rowptr, N);

    fill_kernel<<<CHUNKS * FILL_SUB, 256, 0, stream>>>(srcp, dstp, lr, base, rowptr, csr_src, E);

    const int gw = 4096;
    gemm0_kernel<<<1024, 256, 0, stream>>>(x, W1a[0], yA, N, gw);

    int aggBlocks = (N + 3) / 4;

    agg_kernel<<<aggBlocks, 256, 0, stream>>>(yA, rowptr, csr_src, ubuf, N);
    mlpAB_kernel<0><<<1024, 256, 0, stream>>>(ubuf, b1a[0], W2a[0], b2a[0], W1a[1], Wm, yB, score, N, gw);

    agg_kernel<<<aggBlocks, 256, 0, stream>>>(yB, rowptr, csr_src, ubuf, N);
    mlpAB_kernel<1><<<1024, 256, 0, stream>>>(ubuf, b1a[1], W2a[1], b2a[1], W1a[2], Wm, yA, score, N, gw);

    agg_kernel<<<aggBlocks, 256, 0, stream>>>(yA, rowptr, csr_src, ubuf, N);
    mlpA2_kernel<<<1024, 256, 0, stream>>>(ubuf, b1a[2], W2a[2], b2a[2], Wm, score, N, gw);

    edge_softmax_kernel<<<(N + 3) / 4, 256, 0, stream>>>(score, rowptr, csr_src, bm, nsf, N);

    int nb = (N + 255) / 256;
    gmax_kernel<<<nb, 256, 0, stream>>>(nsf, batch, gmaxu, N);
    gexp_kernel<<<nb, 256, 0, stream>>>(nsf, batch, gmaxu, gsum, out, N);
    gdiv_kernel<<<nb, 256, 0, stream>>>(batch, gsum, out, N);
}